// Round 10
// baseline (215.893 us; speedup 1.0000x reference)
//
#include <hip/hip_runtime.h>
#include <hip/hip_bf16.h>
#include <math.h>

#define D_EMB 256
#define NHEAD 8
#define HD 32
#define NG 64
// 1/sqrt(32) * log2(e): softmax runs in exp2 domain, scale folded into Q
#define QSC 0.25503486f

typedef __attribute__((ext_vector_type(8))) short short8b;   // 8 bf16 (4 VGPR)
typedef __attribute__((ext_vector_type(4))) float f32x4;

__device__ __forceinline__ unsigned int pk2(float a, float b) {
    union { __hip_bfloat162 t; unsigned int u; } r;
    r.t = __float22bfloat162_rn(make_float2(a, b));
    return r.u;
}

// pack two f32x4 score vectors into one bf16x8 fragment
__device__ __forceinline__ short8b pack2v(f32x4 a, f32x4 b) {
    union { unsigned int u[4]; short8b s; } r;
    r.u[0] = pk2(a[0], a[1]);
    r.u[1] = pk2(a[2], a[3]);
    r.u[2] = pk2(b[0], b[1]);
    r.u[3] = pk2(b[2], b[3]);
    return r.s;
}

// ---------------- meta: starts / counts / aligned-starts -------------------
__global__ void k_starts(const int* __restrict__ batch, int n, int* __restrict__ starts) {
    int i = blockIdx.x * blockDim.x + threadIdx.x;
    if (i >= n) return;
    int b = batch[i];
    if (i == 0 || batch[i - 1] != b) starts[b] = i;
}

// counts + 64-aligned per-graph slot starts for the transposed-V buffer
__global__ void k_counts(const int* __restrict__ starts, int n,
                         int* __restrict__ counts, int* __restrict__ astart) {
    if (threadIdx.x != 0) return;
    int a = 0;
    for (int g = 0; g < NG; ++g) {
        int s = starts[g];
        int e = (g == NG - 1) ? n : starts[g + 1];
        int c = e - s;
        counts[g] = c;
        astart[g] = a;
        a += ((c + 63) >> 6) << 6;
    }
}

// ---------------- fp32 -> bf16 bulk convert --------------------------------
__global__ void k_f2bf4(const float* __restrict__ src, unsigned short* __restrict__ dst, int n4) {
    int i = blockIdx.x * blockDim.x + threadIdx.x;
    if (i >= n4) return;
    float4 v = ((const float4*)src)[i];
    uint2 o;
    o.x = pk2(v.x, v.y);
    o.y = pk2(v.z, v.w);
    ((uint2*)dst)[i] = o;
}

// ---------------- bf16 LDS-staged MFMA GEMM --------------------------------
// C = A(Mx256) * W(Nx256)^T.  128x128 tile, 4 waves (2x2), BK=64.
// MODE 0: fp32 out + bias + resid.  MODE 1: bf16 Q(pre-scaled)/K/V split.
#define GLSW 72  // LDS row stride in ushort (144 B, 16B-aligned)

template<int MODE>
__global__ __launch_bounds__(256) void k_gemm(
    const unsigned short* __restrict__ A, const unsigned short* __restrict__ W,
    const float* __restrict__ bias, const float* __restrict__ resid,
    float* __restrict__ Cf, unsigned short* __restrict__ Qb,
    unsigned short* __restrict__ Kb, unsigned short* __restrict__ Vb,
    int M, int Ncols) {
    __shared__ __align__(16) unsigned short Al[128][GLSW];
    __shared__ __align__(16) unsigned short Bl[128][GLSW];

    int tid = threadIdx.x;
    int wave = tid >> 6, lane = tid & 63;
    int lrow = lane & 15, lgrp = lane >> 4;
    int wr = wave >> 1, wc = wave & 1;
    int row0 = blockIdx.x * 128, col0 = blockIdx.y * 128;

    int sr = tid >> 3, sc = (tid & 7) * 8;
    int arow[4], brow[4];
#pragma unroll
    for (int p = 0; p < 4; ++p) {
        int r = sr + p * 32;
        int ar = row0 + r; if (ar >= M) ar = M - 1;
        arow[p] = ar;
        brow[p] = col0 + r;
    }

    f32x4 acc[4][4];
#pragma unroll
    for (int i = 0; i < 4; ++i)
#pragma unroll
        for (int j = 0; j < 4; ++j) acc[i][j] = (f32x4){0.f, 0.f, 0.f, 0.f};

    short8b pa[4], pb[4];
#pragma unroll
    for (int p = 0; p < 4; ++p) {
        pa[p] = *(const short8b*)&A[(size_t)arow[p] * 256 + sc];
        pb[p] = *(const short8b*)&W[(size_t)brow[p] * 256 + sc];
    }

    for (int k0 = 0; k0 < 256; k0 += 64) {
#pragma unroll
        for (int p = 0; p < 4; ++p) {
            int r = sr + p * 32;
            *(short8b*)&Al[r][sc] = pa[p];
            *(short8b*)&Bl[r][sc] = pb[p];
        }
        if (k0 + 64 < 256) {
#pragma unroll
            for (int p = 0; p < 4; ++p) {
                pa[p] = *(const short8b*)&A[(size_t)arow[p] * 256 + k0 + 64 + sc];
                pb[p] = *(const short8b*)&W[(size_t)brow[p] * 256 + k0 + 64 + sc];
            }
        }
        __syncthreads();
#pragma unroll
        for (int half = 0; half < 2; ++half) {
            short8b af[4], bf[4];
#pragma unroll
            for (int mi = 0; mi < 4; ++mi)
                af[mi] = *(const short8b*)&Al[wr * 64 + mi * 16 + lrow][half * 32 + lgrp * 8];
#pragma unroll
            for (int ni = 0; ni < 4; ++ni)
                bf[ni] = *(const short8b*)&Bl[wc * 64 + ni * 16 + lrow][half * 32 + lgrp * 8];
#pragma unroll
            for (int mi = 0; mi < 4; ++mi)
#pragma unroll
                for (int ni = 0; ni < 4; ++ni)
                    acc[mi][ni] = __builtin_amdgcn_mfma_f32_16x16x32_bf16(
                        af[mi], bf[ni], acc[mi][ni], 0, 0, 0);
        }
        __syncthreads();
    }

    if (MODE == 0) {
#pragma unroll
        for (int ni = 0; ni < 4; ++ni) {
            int col = col0 + wc * 64 + ni * 16 + lrow;
            float bv = bias[col];
#pragma unroll
            for (int mi = 0; mi < 4; ++mi) {
                int rowb = row0 + wr * 64 + mi * 16 + lgrp * 4;
#pragma unroll
                for (int r = 0; r < 4; ++r) {
                    int row = rowb + r;
                    if (row < M) {
                        float v = acc[mi][ni][r] + bv;
                        v += resid[(size_t)row * Ncols + col];
                        Cf[(size_t)row * Ncols + col] = v;
                    }
                }
            }
        }
    } else {
        int sel = blockIdx.y >> 1;  // 0:Q 1:K 2:V
        unsigned short* dst = sel == 0 ? Qb : (sel == 1 ? Kb : Vb);
        float qsc = sel == 0 ? QSC : 1.f;
#pragma unroll
        for (int ni = 0; ni < 4; ++ni) {
            int colg = col0 + wc * 64 + ni * 16 + lrow;
            int col = colg & 255;
            float bv = bias[colg];
#pragma unroll
            for (int mi = 0; mi < 4; ++mi) {
                int rowb = row0 + wr * 64 + mi * 16 + lgrp * 4;
#pragma unroll
                for (int r = 0; r < 4; ++r) {
                    int row = rowb + r;
                    if (row < M) {
                        union { __hip_bfloat16 b; unsigned short u; } cv;
                        cv.b = __float2bfloat16((acc[mi][ni][r] + bv) * qsc);
                        dst[(size_t)row * 256 + col] = cv.u;
                    }
                }
            }
        }
    }
}

// ---------------- V transpose: Vb [node][256] -> VtG [h*32+d][slot] --------
// slot = astart[g] + (node - s0); per-graph 64-aligned, tail zero-filled.
__global__ __launch_bounds__(256) void k_vtrans(
    const unsigned short* __restrict__ Vb, const int* __restrict__ starts,
    const int* __restrict__ counts, const int* __restrict__ astart,
    unsigned short* __restrict__ VtG, int Npad) {
    int g = blockIdx.x, h = blockIdx.z;
    int i0 = blockIdx.y * 64;
    int L = counts[g];
    int Lp = (L + 63) & ~63;
    if (i0 >= Lp) return;
    int s0 = starts[g], a0 = astart[g];

    __shared__ unsigned short T[32][72];
    int tid = threadIdx.x;
#pragma unroll
    for (int p = 0; p < 2; ++p) {
        int u = tid + p * 256;
        int node = u >> 3, dc = (u & 7) * 4;
        ushort4 v = make_ushort4(0, 0, 0, 0);
        int nn = i0 + node;
        if (nn < L)
            v = *(const ushort4*)&Vb[(size_t)(s0 + nn) * 256 + h * 32 + dc];
        T[dc + 0][node] = v.x; T[dc + 1][node] = v.y;
        T[dc + 2][node] = v.z; T[dc + 3][node] = v.w;
    }
    __syncthreads();
    int d = tid >> 3, chunk = tid & 7;
    unsigned short* dst = VtG + (size_t)(h * 32 + d) * Npad + a0 + i0 + chunk * 8;
    *(ushort4*)&dst[0] = *(const ushort4*)&T[d][chunk * 8];
    *(ushort4*)&dst[4] = *(const ushort4*)&T[d][chunk * 8 + 4];
}

// ---------------- MFMA attention v7: zero-LDS, zero-barrier ----------------
// One WAVE per (g, h, 32-q tile); 4 independent waves per block, no sync.
// K fragments: direct global b128 (line-perfect). V fragments: b64 loads
// from pre-transposed VtG, k-slot order matching pack2v's P ordering.
// 2-deep software pipeline (A/B register sets) -> loads fly across tiles
// with counted waitcnts; latency hidden by TLP (8192 independent waves).
__global__ __launch_bounds__(256) void k_attn7(
    const unsigned short* __restrict__ Qb, const unsigned short* __restrict__ Kb,
    const unsigned short* __restrict__ VtG, const int* __restrict__ starts,
    const int* __restrict__ counts, const int* __restrict__ astart,
    unsigned short* __restrict__ ctxb, int Npad) {
    int tid = threadIdx.x;
    int wave = tid >> 6, lane = tid & 63;
    int lrow = lane & 15, lgrp = lane >> 4;

    int wid = blockIdx.x * 4 + wave;
    int qt = wid & 15;
    int h = (wid >> 4) & 7;
    int g = wid >> 7;

    int L = counts[g], s0 = starts[g], a0 = astart[g];
    int q0 = qt * 32;
    if (q0 >= L) return;  // wave-uniform exit, no barriers anywhere

    // Q fragments (B-operand: col q = lane&15, k(d) = lgrp*8+j), pre-scaled
    short8b qf[2];
#pragma unroll
    for (int qm = 0; qm < 2; ++qm) {
        int qr = q0 + qm * 16 + lrow;
        if (qr >= L) qr = L - 1;  // clamp; output discarded
        qf[qm] = *(const short8b*)&Qb[(size_t)(s0 + qr) * 256 + h * 32 + lgrp * 8];
    }

    const unsigned short* Kp = Kb + (size_t)s0 * 256 + h * 32 + lgrp * 8;
    const unsigned short* Vp = VtG + (size_t)(h * 32 + lrow) * Npad + a0;

    float lrun[2] = {0.f, 0.f};
    f32x4 acc[2][2];
#pragma unroll
    for (int a = 0; a < 2; ++a) {
        acc[a][0] = (f32x4){0.f, 0.f, 0.f, 0.f};
        acc[a][1] = (f32x4){0.f, 0.f, 0.f, 0.f};
    }

    int nkt = (L + 63) >> 6;

    auto LOADK = [&](short8b (&kf)[4], int kt) {
#pragma unroll
        for (int kn = 0; kn < 4; ++kn)
            kf[kn] = *(const short8b*)&Kp[(size_t)(kt + kn * 16 + lrow) * 256];
        // rows beyond L read following buffers (valid memory); masked below
    };
    auto LOADV = [&](short8b (&vf)[2][2], int kt) {
#pragma unroll
        for (int dsub = 0; dsub < 2; ++dsub)
#pragma unroll
            for (int kh = 0; kh < 2; ++kh) {
                const unsigned short* b = Vp + (size_t)(dsub * 16) * Npad + kt + kh * 32;
                union { ushort4 q[2]; short8b s; } u;
                u.q[0] = *(const ushort4*)&b[lgrp * 4];        // keys kh*32+lgrp*4..+3
                u.q[1] = *(const ushort4*)&b[16 + lgrp * 4];   // keys kh*32+16+lgrp*4..+3
                vf[dsub][kh] = u.s;  // matches pack2v(s[2kh], s[2kh+1]) slot order
            }
    };
    auto COMPUTE = [&](short8b (&kf)[4], short8b (&vf)[2][2], int kt) {
        bool tail = (kt + 64 > L);
        short8b pf[2][2];
#pragma unroll
        for (int qm = 0; qm < 2; ++qm) {
            f32x4 s[4];
#pragma unroll
            for (int kn = 0; kn < 4; ++kn)
                s[kn] = __builtin_amdgcn_mfma_f32_16x16x32_bf16(
                    kf[kn], qf[qm], (f32x4){0.f, 0.f, 0.f, 0.f}, 0, 0, 0);
            if (tail) {
#pragma unroll
                for (int kn = 0; kn < 4; ++kn)
#pragma unroll
                    for (int r = 0; r < 4; ++r) {
                        int key = kt + kn * 16 + lgrp * 4 + r;
                        if (key >= L) s[kn][r] = -INFINITY;
                    }
            }
            float ps = lrun[qm];
#pragma unroll
            for (int kn = 0; kn < 4; ++kn)
#pragma unroll
                for (int r = 0; r < 4; ++r) {
                    float pv = exp2f(fminf(s[kn][r], 80.f));
                    s[kn][r] = pv;
                    ps += pv;
                }
            lrun[qm] = ps;
            pf[qm][0] = pack2v(s[0], s[1]);
            pf[qm][1] = pack2v(s[2], s[3]);
        }
#pragma unroll
        for (int qm = 0; qm < 2; ++qm)
#pragma unroll
            for (int dsub = 0; dsub < 2; ++dsub) {
                acc[qm][dsub] = __builtin_amdgcn_mfma_f32_16x16x32_bf16(
                    vf[dsub][0], pf[qm][0], acc[qm][dsub], 0, 0, 0);
                acc[qm][dsub] = __builtin_amdgcn_mfma_f32_16x16x32_bf16(
                    vf[dsub][1], pf[qm][1], acc[qm][dsub], 0, 0, 0);
            }
    };

    short8b kfA[4], kfB[4];
    short8b vfA[2][2], vfB[2][2];
    LOADK(kfA, 0);
    LOADV(vfA, 0);
    for (int t = 0; t < nkt; t += 2) {
        if (t + 1 < nkt) { LOADK(kfB, (t + 1) * 64); LOADV(vfB, (t + 1) * 64); }
        COMPUTE(kfA, vfA, t * 64);
        if (t + 1 >= nkt) break;
        if (t + 2 < nkt) { LOADK(kfA, (t + 2) * 64); LOADV(vfA, (t + 2) * 64); }
        COMPUTE(kfB, vfB, (t + 1) * 64);
    }

    // epilogue: reduce row sums, normalize, store bf16
#pragma unroll
    for (int qm = 0; qm < 2; ++qm) {
        int q = q0 + qm * 16 + lrow;
        float tsum = lrun[qm];
        tsum += __shfl_xor(tsum, 16);
        tsum += __shfl_xor(tsum, 32);
        if (q >= L) continue;
        float inv = 1.f / tsum;
        unsigned short* dst = ctxb + (size_t)(s0 + q) * 256 + h * 32;
#pragma unroll
        for (int dsub = 0; dsub < 2; ++dsub) {
#pragma unroll
            for (int rp = 0; rp < 4; rp += 2) {
                *(unsigned int*)&dst[dsub * 16 + lgrp * 4 + rp] =
                    pk2(acc[qm][dsub][rp] * inv, acc[qm][dsub][rp + 1] * inv);
            }
        }
    }
}

// ---------------- per-graph LN stats: 4 partial blocks per graph -----------
__global__ __launch_bounds__(256) void k_stats_part(
    const float* __restrict__ hbuf, const int* __restrict__ starts,
    const int* __restrict__ counts, float* __restrict__ part) {
    int g = blockIdx.x, qq = blockIdx.y;
    int s0 = starts[g], cnt = counts[g];
    int cq = (cnt + 3) >> 2;
    int r0 = qq * cq;
    int r1 = min(cnt, r0 + cq);

    float sum = 0.f, sq = 0.f;
    if (r0 < r1) {
        const float4* p = (const float4*)(hbuf + (size_t)(s0 + r0) * D_EMB);
        size_t n4 = (size_t)(r1 - r0) * (D_EMB / 4);
        for (size_t i = threadIdx.x; i < n4; i += 256) {
            float4 v = p[i];
            sum += v.x + v.y + v.z + v.w;
            sq += v.x * v.x + v.y * v.y + v.z * v.z + v.w * v.w;
        }
    }
#pragma unroll
    for (int o = 32; o > 0; o >>= 1) {
        sum += __shfl_down(sum, o);
        sq += __shfl_down(sq, o);
    }
    __shared__ float ssum[4], ssq[4];
    int wid = threadIdx.x >> 6, lane = threadIdx.x & 63;
    if (lane == 0) { ssum[wid] = sum; ssq[wid] = sq; }
    __syncthreads();
    if (threadIdx.x == 0) {
        float S = 0.f, Q = 0.f;
#pragma unroll
        for (int w = 0; w < 4; ++w) { S += ssum[w]; Q += ssq[w]; }
        part[(g * 4 + qq) * 2] = S;
        part[(g * 4 + qq) * 2 + 1] = Q;
    }
}

__global__ void k_stats_final(const float* __restrict__ part,
                              const int* __restrict__ counts,
                              float* __restrict__ stats) {
    int g = threadIdx.x;
    if (g >= NG) return;
    float S = 0.f, Q = 0.f;
#pragma unroll
    for (int i = 0; i < 4; ++i) {
        S += part[(g * 4 + i) * 2];
        Q += part[(g * 4 + i) * 2 + 1];
    }
    float norm = (float)counts[g] * (float)D_EMB;
    float mean = S / norm;
    float var = Q / norm - mean * mean;
    stats[2 * g] = mean;
    stats[2 * g + 1] = rsqrtf(var + 1e-5f);
}

// ---------------- LN apply + exact GELU, in place --------------------------
__global__ void k_ln_gelu(float* __restrict__ h, const int* __restrict__ batch,
                          const float* __restrict__ stats, const float* __restrict__ lw,
                          const float* __restrict__ lb, int n) {
    int idx = blockIdx.x * blockDim.x + threadIdx.x;
    if (idx >= n * (D_EMB / 4)) return;
    int row = idx >> 6;
    int c4 = idx & 63;
    int g = batch[row];
    float mean = stats[2 * g], inv = stats[2 * g + 1];
    float4 v = *(float4*)&h[(size_t)idx * 4];
    float4 wv = *(const float4*)&lw[c4 * 4];
    float4 bv = *(const float4*)&lb[c4 * 4];
    float y;
    y = (v.x - mean) * inv * wv.x + bv.x; v.x = 0.5f * y * (1.f + erff(y * 0.70710678118f));
    y = (v.y - mean) * inv * wv.y + bv.y; v.y = 0.5f * y * (1.f + erff(y * 0.70710678118f));
    y = (v.z - mean) * inv * wv.z + bv.z; v.z = 0.5f * y * (1.f + erff(y * 0.70710678118f));
    y = (v.w - mean) * inv * wv.w + bv.w; v.w = 0.5f * y * (1.f + erff(y * 0.70710678118f));
    *(float4*)&h[(size_t)idx * 4] = v;
}

// ---------------- launch ----------------------------------------------------
extern "C" void kernel_launch(void* const* d_in, const int* in_sizes, int n_in,
                              void* d_out, int out_size, void* d_ws, size_t ws_size,
                              hipStream_t stream) {
    const float* x     = (const float*)d_in[0];
    const int*   batch = (const int*)d_in[1];
    const float* in_w  = (const float*)d_in[2];
    const float* in_b  = (const float*)d_in[3];
    const float* out_w = (const float*)d_in[4];
    const float* out_b = (const float*)d_in[5];
    const float* ln_w  = (const float*)d_in[6];
    const float* ln_b  = (const float*)d_in[7];
    int N = in_sizes[1];
    float* out = (float*)d_out;
    int Npad = N + 4096;  // worst-case 64-aligned per-graph padding

    char* ws = (char*)d_ws;
    int*   starts = (int*)ws;                         // 64 ints
    int*   counts = starts + 64;                      // 64 ints
    float* stats  = (float*)(ws + 512);               // 128 floats
    float* part   = (float*)(ws + 1024);              // 512 floats
    int*   astart = (int*)(ws + 3072);                // 64 ints
    unsigned short* xb   = (unsigned short*)(ws + 4096);
    unsigned short* wb1  = xb + (size_t)N * 256;
    unsigned short* wb2  = wb1 + 768 * 256;
    unsigned short* Qb   = wb2 + 256 * 256;
    unsigned short* Kb   = Qb + (size_t)N * 256;
    unsigned short* Vb   = Kb + (size_t)N * 256;      // K-tail overrun lands here (masked)
    unsigned short* ctxb = Vb + (size_t)N * 256;
    unsigned short* VtG  = ctxb + (size_t)N * 256;    // [256][Npad]

    k_starts<<<(N + 255) / 256, 256, 0, stream>>>(batch, N, starts);
    k_counts<<<1, 64, 0, stream>>>(starts, N, counts, astart);

    int n4x = N * 64;
    k_f2bf4<<<(n4x + 255) / 256, 256, 0, stream>>>(x, xb, n4x);
    k_f2bf4<<<(768 * 64 + 255) / 256, 256, 0, stream>>>(in_w, wb1, 768 * 64);
    k_f2bf4<<<(256 * 64 + 255) / 256, 256, 0, stream>>>(out_w, wb2, 256 * 64);

    dim3 g1((N + 127) / 128, 6);
    k_gemm<1><<<g1, 256, 0, stream>>>(xb, wb1, in_b, nullptr, nullptr,
                                      Qb, Kb, Vb, N, 768);

    k_vtrans<<<dim3(NG, 8, NHEAD), 256, 0, stream>>>(Vb, starts, counts, astart, VtG, Npad);

    k_attn7<<<NG * NHEAD * 16 / 4, 256, 0, stream>>>(Qb, Kb, VtG, starts, counts,
                                                     astart, ctxb, Npad);

    dim3 g3((N + 127) / 128, 2);
    k_gemm<0><<<g3, 256, 0, stream>>>(ctxb, wb2, out_b, x, out,
                                      nullptr, nullptr, nullptr, N, 256);

    k_stats_part<<<dim3(NG, 4), 256, 0, stream>>>(out, starts, counts, part);
    k_stats_final<<<1, 64, 0, stream>>>(part, counts, stats);

    int nv4 = N * (D_EMB / 4);
    k_ln_gelu<<<(nv4 + 255) / 256, 256, 0, stream>>>(out, batch, stats, ln_w, ln_b, N);
}

// Round 11
// 181.588 us; speedup vs baseline: 1.1889x; 1.1889x over previous
//
#include <hip/hip_runtime.h>
#include <hip/hip_bf16.h>
#include <math.h>

#define D_EMB 256
#define NHEAD 8
#define HD 32
#define NG 64
// 1/sqrt(32) * log2(e): softmax runs in exp2 domain, scale folded into Q
#define QSC 0.25503486f

typedef __attribute__((ext_vector_type(8))) short short8b;   // 8 bf16 (4 VGPR)
typedef __attribute__((ext_vector_type(4))) float f32x4;

__device__ __forceinline__ unsigned int pk2(float a, float b) {
    union { __hip_bfloat162 t; unsigned int u; } r;
    r.t = __float22bfloat162_rn(make_float2(a, b));
    return r.u;
}

// pack two f32x4 score vectors into one bf16x8 fragment
__device__ __forceinline__ short8b pack2v(f32x4 a, f32x4 b) {
    union { unsigned int u[4]; short8b s; } r;
    r.u[0] = pk2(a[0], a[1]);
    r.u[1] = pk2(a[2], a[3]);
    r.u[2] = pk2(b[0], b[1]);
    r.u[3] = pk2(b[2], b[3]);
    return r.s;
}

// Barrier WITHOUT the compiler's vmcnt(0) drain: LDS visibility needs only
// lgkmcnt; prefetched global->REG loads legally stay in flight (their
// counted vmcnt waits sit at first use, compiler-inserted).
__device__ __forceinline__ void barrier_lgkm() {
    asm volatile("s_waitcnt lgkmcnt(0)" ::: "memory");
    __builtin_amdgcn_s_barrier();
}

// ---------------- meta: starts / counts from sorted batch ----------------
__global__ void k_starts(const int* __restrict__ batch, int n, int* __restrict__ starts) {
    int i = blockIdx.x * blockDim.x + threadIdx.x;
    if (i >= n) return;
    int b = batch[i];
    if (i == 0 || batch[i - 1] != b) starts[b] = i;
}

__global__ void k_counts(const int* __restrict__ starts, int n, int* __restrict__ counts) {
    int g = threadIdx.x;
    if (g < NG) {
        int s = starts[g];
        int e = (g == NG - 1) ? n : starts[g + 1];
        counts[g] = e - s;
    }
}

// ---------------- fp32 -> bf16 bulk convert --------------------------------
__global__ void k_f2bf4(const float* __restrict__ src, unsigned short* __restrict__ dst, int n4) {
    int i = blockIdx.x * blockDim.x + threadIdx.x;
    if (i >= n4) return;
    float4 v = ((const float4*)src)[i];
    uint2 o;
    o.x = pk2(v.x, v.y);
    o.y = pk2(v.z, v.w);
    ((uint2*)dst)[i] = o;
}

// ---------------- bf16 LDS-staged MFMA GEMM --------------------------------
// C = A(Mx256) * W(Nx256)^T.  128x128 tile, 4 waves (2x2), BK=64.
// Cross-iteration global->reg prefetch + raw barriers (no vmcnt drain):
// loads for k0+64 genuinely overlap the 32-MFMA compute phase.
// MODE 0: fp32 out + bias + resid.  MODE 1: bf16 Q(pre-scaled)/K/V split.
#define GLSW 72  // LDS row stride in ushort (144 B, 16B-aligned)

template<int MODE>
__global__ __launch_bounds__(256) void k_gemm(
    const unsigned short* __restrict__ A, const unsigned short* __restrict__ W,
    const float* __restrict__ bias, const float* __restrict__ resid,
    float* __restrict__ Cf, unsigned short* __restrict__ Qb,
    unsigned short* __restrict__ Kb, unsigned short* __restrict__ Vb,
    int M, int Ncols) {
    __shared__ __align__(16) unsigned short Al[128][GLSW];
    __shared__ __align__(16) unsigned short Bl[128][GLSW];

    int tid = threadIdx.x;
    int wave = tid >> 6, lane = tid & 63;
    int lrow = lane & 15, lgrp = lane >> 4;
    int wr = wave >> 1, wc = wave & 1;
    int row0 = blockIdx.x * 128, col0 = blockIdx.y * 128;

    int sr = tid >> 3, sc = (tid & 7) * 8;
    int arow[4], brow[4];
#pragma unroll
    for (int p = 0; p < 4; ++p) {
        int r = sr + p * 32;
        int ar = row0 + r; if (ar >= M) ar = M - 1;
        arow[p] = ar;
        brow[p] = col0 + r;
    }

    f32x4 acc[4][4];
#pragma unroll
    for (int i = 0; i < 4; ++i)
#pragma unroll
        for (int j = 0; j < 4; ++j) acc[i][j] = (f32x4){0.f, 0.f, 0.f, 0.f};

    short8b pa[4], pb[4];
#pragma unroll
    for (int p = 0; p < 4; ++p) {
        pa[p] = *(const short8b*)&A[(size_t)arow[p] * 256 + sc];
        pb[p] = *(const short8b*)&W[(size_t)brow[p] * 256 + sc];
    }

    for (int k0 = 0; k0 < 256; k0 += 64) {
#pragma unroll
        for (int p = 0; p < 4; ++p) {
            int r = sr + p * 32;
            *(short8b*)&Al[r][sc] = pa[p];
            *(short8b*)&Bl[r][sc] = pb[p];
        }
        if (k0 + 64 < 256) {
#pragma unroll
            for (int p = 0; p < 4; ++p) {
                pa[p] = *(const short8b*)&A[(size_t)arow[p] * 256 + k0 + 64 + sc];
                pb[p] = *(const short8b*)&W[(size_t)brow[p] * 256 + k0 + 64 + sc];
            }
        }
        barrier_lgkm();  // LDS writes visible; prefetch stays in flight
#pragma unroll
        for (int half = 0; half < 2; ++half) {
            short8b af[4], bf[4];
#pragma unroll
            for (int mi = 0; mi < 4; ++mi)
                af[mi] = *(const short8b*)&Al[wr * 64 + mi * 16 + lrow][half * 32 + lgrp * 8];
#pragma unroll
            for (int ni = 0; ni < 4; ++ni)
                bf[ni] = *(const short8b*)&Bl[wc * 64 + ni * 16 + lrow][half * 32 + lgrp * 8];
#pragma unroll
            for (int mi = 0; mi < 4; ++mi)
#pragma unroll
                for (int ni = 0; ni < 4; ++ni)
                    acc[mi][ni] = __builtin_amdgcn_mfma_f32_16x16x32_bf16(
                        af[mi], bf[ni], acc[mi][ni], 0, 0, 0);
        }
        barrier_lgkm();  // all reads (consumed by MFMAs) done before rewrite
    }

    if (MODE == 0) {
#pragma unroll
        for (int ni = 0; ni < 4; ++ni) {
            int col = col0 + wc * 64 + ni * 16 + lrow;
            float bv = bias[col];
#pragma unroll
            for (int mi = 0; mi < 4; ++mi) {
                int rowb = row0 + wr * 64 + mi * 16 + lgrp * 4;
#pragma unroll
                for (int r = 0; r < 4; ++r) {
                    int row = rowb + r;
                    if (row < M) {
                        float v = acc[mi][ni][r] + bv;
                        v += resid[(size_t)row * Ncols + col];
                        Cf[(size_t)row * Ncols + col] = v;
                    }
                }
            }
        }
    } else {
        int sel = blockIdx.y >> 1;  // 0:Q 1:K 2:V
        unsigned short* dst = sel == 0 ? Qb : (sel == 1 ? Kb : Vb);
        float qsc = sel == 0 ? QSC : 1.f;
#pragma unroll
        for (int ni = 0; ni < 4; ++ni) {
            int colg = col0 + wc * 64 + ni * 16 + lrow;
            int col = colg & 255;
            float bv = bias[colg];
#pragma unroll
            for (int mi = 0; mi < 4; ++mi) {
                int rowb = row0 + wr * 64 + mi * 16 + lgrp * 4;
#pragma unroll
                for (int r = 0; r < 4; ++r) {
                    int row = rowb + r;
                    if (row < M) {
                        union { __hip_bfloat16 b; unsigned short u; } cv;
                        cv.b = __float2bfloat16((acc[mi][ni][r] + bv) * qsc);
                        dst[(size_t)row * 256 + col] = cv.u;
                    }
                }
            }
        }
    }
}

// ---------------- MFMA attention v6b ----------------------------------------
// grid = (graph, head, 4 q-chunks of 128); block = 4 waves x 32 q.
// Double-buffered 64-key tiles, ONE raw barrier per tile (lgkm-only):
// write staged tile t, issue reg-loads t+1 (STAY IN FLIGHT across barrier),
// barrier, compute. Static-max softmax in exp2 domain.
#define KSW 40  // Klds row stride (ushort), 80 B, 16B-aligned
#define VSW 76  // Vt row stride (ushort), 152 B, 8B-aligned, odd-dword banks

__global__ __launch_bounds__(256) void k_attn6(
    const unsigned short* __restrict__ Qb, const unsigned short* __restrict__ Kb,
    const unsigned short* __restrict__ Vb, const int* __restrict__ starts,
    const int* __restrict__ counts, unsigned short* __restrict__ ctxb) {
    int g = blockIdx.x, h = blockIdx.y, chunk = blockIdx.z;
    int L = counts[g], s0 = starts[g];
    if (chunk * 128 >= L) return;

    __shared__ __align__(16) unsigned short Klds[2][64][KSW];  // 10240 B
    __shared__ __align__(16) unsigned short Vt[2][32][VSW];    //  9728 B

    int tid = threadIdx.x;
    int wave = tid >> 6, lane = tid & 63;
    int lrow = lane & 15, lgrp = lane >> 4;
    int qbase = chunk * 128 + wave * 32;

    // Q fragments (B-operand: col q = lane&15, k(d) = lgrp*8+j), pre-scaled
    short8b qf[2];
#pragma unroll
    for (int qm = 0; qm < 2; ++qm) {
        int qr = qbase + qm * 16 + lrow;
        if (qr >= L) qr = L - 1;  // clamp; output discarded
        qf[qm] = *(const short8b*)&Qb[(size_t)(s0 + qr) * 256 + h * 32 + lgrp * 8];
    }

    // staging indices
    int skey = tid >> 2, skc = (tid & 3) * 8;       // K: 1 b128 per thread
    int vu = tid >> 3, vd4 = (tid & 7) * 4;         // V: keys 2u,2u+1, d4..d4+3

    // prologue: load tile 0 into regs
    short8b kreg;
    ushort4 vreg0, vreg1;
    {
        int kr = skey < L ? skey : L - 1;
        kreg = *(const short8b*)&Kb[(size_t)(s0 + kr) * 256 + h * 32 + skc];
        int v0 = (2 * vu) < L ? (2 * vu) : L - 1;
        int v1 = (2 * vu + 1) < L ? (2 * vu + 1) : L - 1;
        vreg0 = *(const ushort4*)&Vb[(size_t)(s0 + v0) * 256 + h * 32 + vd4];
        vreg1 = *(const ushort4*)&Vb[(size_t)(s0 + v1) * 256 + h * 32 + vd4];
    }

    float lrun[2] = {0.f, 0.f};  // per-lane partial sums; reduced in epilogue
    f32x4 acc[2][2];
#pragma unroll
    for (int a = 0; a < 2; ++a) {
        acc[a][0] = (f32x4){0.f, 0.f, 0.f, 0.f};
        acc[a][1] = (f32x4){0.f, 0.f, 0.f, 0.f};
    }

    int nkt = (L + 63) >> 6;
    for (int t = 0; t < nkt; ++t) {
        int kt = t * 64;
        int buf = t & 1;

        // ---- write staged tile t into LDS buf (vmcnt waits at use only) ----
        *(short8b*)&Klds[buf][skey][skc] = kreg;
#pragma unroll
        for (int j = 0; j < 4; ++j) {
            unsigned int pr = (unsigned int)(unsigned short)(&vreg0.x)[j] |
                              ((unsigned int)(unsigned short)(&vreg1.x)[j] << 16);
            *(unsigned int*)&Vt[buf][vd4 + j][2 * vu] = pr;
        }

        // ---- issue loads for tile t+1: remain in flight across barrier ----
        if (t + 1 < nkt) {
            int ktn = kt + 64;
            int kr = (ktn + skey) < L ? (ktn + skey) : L - 1;
            kreg = *(const short8b*)&Kb[(size_t)(s0 + kr) * 256 + h * 32 + skc];
            int v0 = (ktn + 2 * vu) < L ? (ktn + 2 * vu) : L - 1;
            int v1 = (ktn + 2 * vu + 1) < L ? (ktn + 2 * vu + 1) : L - 1;
            vreg0 = *(const ushort4*)&Vb[(size_t)(s0 + v0) * 256 + h * 32 + vd4];
            vreg1 = *(const ushort4*)&Vb[(size_t)(s0 + v1) * 256 + h * 32 + vd4];
        }

        barrier_lgkm();  // LDS t staged & visible; t-1 reads (other buf) done

        // ---- compute tile t from buf ----
        short8b kf[4];
#pragma unroll
        for (int kn = 0; kn < 4; ++kn)
            kf[kn] = *(const short8b*)&Klds[buf][kn * 16 + lrow][lgrp * 8];
        short8b vf[2][2];
#pragma unroll
        for (int dsub = 0; dsub < 2; ++dsub)
#pragma unroll
            for (int kh = 0; kh < 2; ++kh) {
                ushort4 lo = *(const ushort4*)&Vt[buf][dsub * 16 + lrow][kh * 32 + lgrp * 4];
                ushort4 hi = *(const ushort4*)&Vt[buf][dsub * 16 + lrow][kh * 32 + 16 + lgrp * 4];
                union { ushort4 q[2]; short8b s; } u;
                u.q[0] = lo; u.q[1] = hi;
                vf[dsub][kh] = u.s;
            }

        bool tail = (kt + 64 > L);
        short8b pf[2][2];
#pragma unroll
        for (int qm = 0; qm < 2; ++qm) {
            f32x4 s[4];
#pragma unroll
            for (int kn = 0; kn < 4; ++kn)
                s[kn] = __builtin_amdgcn_mfma_f32_16x16x32_bf16(
                    kf[kn], qf[qm], (f32x4){0.f, 0.f, 0.f, 0.f}, 0, 0, 0);
            if (tail) {
#pragma unroll
                for (int kn = 0; kn < 4; ++kn)
#pragma unroll
                    for (int r = 0; r < 4; ++r) {
                        int key = kt + kn * 16 + lgrp * 4 + r;
                        if (key >= L) s[kn][r] = -INFINITY;
                    }
            }
            // static-max softmax numerator: pv = exp2(s), fp32-safe via clamp
            float ps = lrun[qm];
#pragma unroll
            for (int kn = 0; kn < 4; ++kn)
#pragma unroll
                for (int r = 0; r < 4; ++r) {
                    float pv = exp2f(fminf(s[kn][r], 80.f));
                    s[kn][r] = pv;
                    ps += pv;
                }
            lrun[qm] = ps;
            pf[qm][0] = pack2v(s[0], s[1]);
            pf[qm][1] = pack2v(s[2], s[3]);
        }

        // PV: O^T += V^T P^T (natural key order on both sides)
#pragma unroll
        for (int qm = 0; qm < 2; ++qm)
#pragma unroll
            for (int dsub = 0; dsub < 2; ++dsub) {
                acc[qm][dsub] = __builtin_amdgcn_mfma_f32_16x16x32_bf16(
                    vf[dsub][0], pf[qm][0], acc[qm][dsub], 0, 0, 0);
                acc[qm][dsub] = __builtin_amdgcn_mfma_f32_16x16x32_bf16(
                    vf[dsub][1], pf[qm][1], acc[qm][dsub], 0, 0, 0);
            }
        // no trailing barrier: next iter writes the OTHER buffer; the next
        // barrier orders those writes vs. this tile's reads across waves
    }

    // epilogue: reduce row sums (once), normalize, store bf16
#pragma unroll
    for (int qm = 0; qm < 2; ++qm) {
        int q = qbase + qm * 16 + lrow;
        float tsum = lrun[qm];
        tsum += __shfl_xor(tsum, 16);
        tsum += __shfl_xor(tsum, 32);
        if (q >= L) continue;
        float inv = 1.f / tsum;
        unsigned short* dst = ctxb + (size_t)(s0 + q) * 256 + h * 32;
#pragma unroll
        for (int dsub = 0; dsub < 2; ++dsub) {
#pragma unroll
            for (int rp = 0; rp < 4; rp += 2) {
                *(unsigned int*)&dst[dsub * 16 + lgrp * 4 + rp] =
                    pk2(acc[qm][dsub][rp] * inv, acc[qm][dsub][rp + 1] * inv);
            }
        }
    }
}

// ---------------- per-graph LN stats: 4 partial blocks per graph -----------
__global__ __launch_bounds__(256) void k_stats_part(
    const float* __restrict__ hbuf, const int* __restrict__ starts,
    const int* __restrict__ counts, float* __restrict__ part) {
    int g = blockIdx.x, qq = blockIdx.y;
    int s0 = starts[g], cnt = counts[g];
    int cq = (cnt + 3) >> 2;
    int r0 = qq * cq;
    int r1 = min(cnt, r0 + cq);

    float sum = 0.f, sq = 0.f;
    if (r0 < r1) {
        const float4* p = (const float4*)(hbuf + (size_t)(s0 + r0) * D_EMB);
        size_t n4 = (size_t)(r1 - r0) * (D_EMB / 4);
        for (size_t i = threadIdx.x; i < n4; i += 256) {
            float4 v = p[i];
            sum += v.x + v.y + v.z + v.w;
            sq += v.x * v.x + v.y * v.y + v.z * v.z + v.w * v.w;
        }
    }
#pragma unroll
    for (int o = 32; o > 0; o >>= 1) {
        sum += __shfl_down(sum, o);
        sq += __shfl_down(sq, o);
    }
    __shared__ float ssum[4], ssq[4];
    int wid = threadIdx.x >> 6, lane = threadIdx.x & 63;
    if (lane == 0) { ssum[wid] = sum; ssq[wid] = sq; }
    __syncthreads();
    if (threadIdx.x == 0) {
        float S = 0.f, Q = 0.f;
#pragma unroll
        for (int w = 0; w < 4; ++w) { S += ssum[w]; Q += ssq[w]; }
        part[(g * 4 + qq) * 2] = S;
        part[(g * 4 + qq) * 2 + 1] = Q;
    }
}

__global__ void k_stats_final(const float* __restrict__ part,
                              const int* __restrict__ counts,
                              float* __restrict__ stats) {
    int g = threadIdx.x;
    if (g >= NG) return;
    float S = 0.f, Q = 0.f;
#pragma unroll
    for (int i = 0; i < 4; ++i) {
        S += part[(g * 4 + i) * 2];
        Q += part[(g * 4 + i) * 2 + 1];
    }
    float norm = (float)counts[g] * (float)D_EMB;
    float mean = S / norm;
    float var = Q / norm - mean * mean;
    stats[2 * g] = mean;
    stats[2 * g + 1] = rsqrtf(var + 1e-5f);
}

// ---------------- LN apply + exact GELU, in place --------------------------
__global__ void k_ln_gelu(float* __restrict__ h, const int* __restrict__ batch,
                          const float* __restrict__ stats, const float* __restrict__ lw,
                          const float* __restrict__ lb, int n) {
    int idx = blockIdx.x * blockDim.x + threadIdx.x;
    if (idx >= n * (D_EMB / 4)) return;
    int row = idx >> 6;
    int c4 = idx & 63;
    int g = batch[row];
    float mean = stats[2 * g], inv = stats[2 * g + 1];
    float4 v = *(float4*)&h[(size_t)idx * 4];
    float4 wv = *(const float4*)&lw[c4 * 4];
    float4 bv = *(const float4*)&lb[c4 * 4];
    float y;
    y = (v.x - mean) * inv * wv.x + bv.x; v.x = 0.5f * y * (1.f + erff(y * 0.70710678118f));
    y = (v.y - mean) * inv * wv.y + bv.y; v.y = 0.5f * y * (1.f + erff(y * 0.70710678118f));
    y = (v.z - mean) * inv * wv.z + bv.z; v.z = 0.5f * y * (1.f + erff(y * 0.70710678118f));
    y = (v.w - mean) * inv * wv.w + bv.w; v.w = 0.5f * y * (1.f + erff(y * 0.70710678118f));
    *(float4*)&h[(size_t)idx * 4] = v;
}

// ---------------- launch ----------------------------------------------------
extern "C" void kernel_launch(void* const* d_in, const int* in_sizes, int n_in,
                              void* d_out, int out_size, void* d_ws, size_t ws_size,
                              hipStream_t stream) {
    const float* x     = (const float*)d_in[0];
    const int*   batch = (const int*)d_in[1];
    const float* in_w  = (const float*)d_in[2];
    const float* in_b  = (const float*)d_in[3];
    const float* out_w = (const float*)d_in[4];
    const float* out_b = (const float*)d_in[5];
    const float* ln_w  = (const float*)d_in[6];
    const float* ln_b  = (const float*)d_in[7];
    int N = in_sizes[1];
    float* out = (float*)d_out;

    char* ws = (char*)d_ws;
    int*   starts = (int*)ws;                         // 64 ints
    int*   counts = starts + 64;                      // 64 ints
    float* stats  = (float*)(ws + 512);               // 128 floats
    float* part   = (float*)(ws + 1024);              // 512 floats
    unsigned short* xb   = (unsigned short*)(ws + 3072);
    unsigned short* wb1  = xb + (size_t)N * 256;
    unsigned short* wb2  = wb1 + 768 * 256;
    unsigned short* Qb   = wb2 + 256 * 256;
    unsigned short* Kb   = Qb + (size_t)N * 256;
    unsigned short* Vb   = Kb + (size_t)N * 256;
    unsigned short* ctxb = Vb + (size_t)N * 256;

    k_starts<<<(N + 255) / 256, 256, 0, stream>>>(batch, N, starts);
    k_counts<<<1, 64, 0, stream>>>(starts, N, counts);

    int n4x = N * 64;
    k_f2bf4<<<(n4x + 255) / 256, 256, 0, stream>>>(x, xb, n4x);
    k_f2bf4<<<(768 * 64 + 255) / 256, 256, 0, stream>>>(in_w, wb1, 768 * 64);
    k_f2bf4<<<(256 * 64 + 255) / 256, 256, 0, stream>>>(out_w, wb2, 256 * 64);

    dim3 g1((N + 127) / 128, 6);
    k_gemm<1><<<g1, 256, 0, stream>>>(xb, wb1, in_b, nullptr, nullptr,
                                      Qb, Kb, Vb, N, 768);

    k_attn6<<<dim3(NG, NHEAD, 4), 256, 0, stream>>>(Qb, Kb, Vb, starts, counts, ctxb);

    dim3 g3((N + 127) / 128, 2);
    k_gemm<0><<<g3, 256, 0, stream>>>(ctxb, wb2, out_b, x, out,
                                      nullptr, nullptr, nullptr, N, 256);

    k_stats_part<<<dim3(NG, 4), 256, 0, stream>>>(out, starts, counts, part);
    k_stats_final<<<1, 64, 0, stream>>>(part, counts, stats);

    int nv4 = N * (D_EMB / 4);
    k_ln_gelu<<<(nv4 + 255) / 256, 256, 0, stream>>>(out, batch, stats, ln_w, ln_b, N);
}